// Round 1
// 524.860 us; speedup vs baseline: 1.0022x; 1.0022x over previous
//
#include <hip/hip_runtime.h>
#include <math.h>

#define B_   1024
#define N_   200
#define NR_  208      // padded rows (13 x 16)
#define NT_  13
#define E_   256
#define R_   256
#define K6_  1536

typedef __attribute__((ext_vector_type(8))) short bf16x8;
typedef __attribute__((ext_vector_type(4))) float f32x4;

__device__ __forceinline__ unsigned short f2bf(float f) {
  unsigned int u = __float_as_uint(f);
  u += 0x7fffu + ((u >> 16) & 1u);          // RNE
  return (unsigned short)(u >> 16);
}

__device__ __forceinline__ float gelu_exact(float x) {
  return 0.5f * x * (1.f + erff(x * 0.70710678118654752f));
}

// ---------------- cast rel_w and sp_w to bf16 in ws ----------------
__global__ __launch_bounds__(256) void k_cast(const float* __restrict__ rel_w,
                                              const float* __restrict__ sp_w,
                                              unsigned short* __restrict__ rw_bf,
                                              unsigned short* __restrict__ spw_bf) {
  int idx = blockIdx.x * 256 + threadIdx.x;
  if (idx < E_ * R_) rw_bf[idx] = f2bf(rel_w[idx]);
  int j = idx - E_ * R_;
  if (j >= 0 && j < 3 * E_ * K6_) spw_bf[j] = f2bf(sp_w[j]);
}

// ------- k_prep: fused q_key -> (csq logits, wts) -> q_proj -> t  -------
// (unchanged this round — isolate the k1 delta; candidate for next round)
__global__ __launch_bounds__(256) void k_prep(
    const float* __restrict__ r_emb, const float* __restrict__ rel_w,
    const float* __restrict__ csq_w, const float* __restrict__ csq_b,
    const float* __restrict__ csl_w, const float* __restrict__ csl_b,
    const float* __restrict__ attn_w,
    float* __restrict__ t_ws, float* __restrict__ wts) {
  __shared__ __align__(16) float re[4][256];
  __shared__ __align__(16) float qk[4][256];
  __shared__ __align__(16) float sqs[4][256];
  __shared__ __align__(16) float qp[3][4][256];
  __shared__ float lg[4][3];
  int b0 = blockIdx.x * 4;
  int tid = threadIdx.x;
  int e = tid;
#pragma unroll
  for (int i = 0; i < 4; ++i)
    re[i][tid] = r_emb[(size_t)(b0 + i) * 256 + tid];
  __syncthreads();
  {
    float qkv[4], sv[4];
#pragma unroll
    for (int i = 0; i < 4; ++i) { qkv[i] = 0.f; sv[i] = 0.f; }
    const float4* w4 = (const float4*)(rel_w) + (size_t)e * 64;
    const float4* c4 = (const float4*)(csq_w) + (size_t)e * 64;
    for (int r = 0; r < 64; ++r) {
      float4 w = w4[r];
      float4 c = c4[r];
#pragma unroll
      for (int i = 0; i < 4; ++i) {
        float4 x = ((const float4*)re[i])[r];
        qkv[i] += w.x * x.x + w.y * x.y + w.z * x.z + w.w * x.w;
        sv[i] += c.x * x.x + c.y * x.y + c.z * x.z + c.w * x.w;
      }
    }
    float cb = csq_b[e];
#pragma unroll
    for (int i = 0; i < 4; ++i) {
      qk[i][e] = qkv[i];
      sqs[i][e] = sv[i] + cb;
    }
  }
  __syncthreads();
  if (tid < 12) {
    int i = tid / 3, k = tid % 3;
    float acc = csl_b[k];
    for (int ee = 0; ee < 256; ++ee) acc += sqs[i][ee] * csl_w[k * 256 + ee];
    lg[i][k] = acc;
  }
  __syncthreads();
  if (tid < 4) {
    float l0 = lg[tid][0], l1 = lg[tid][1], l2 = lg[tid][2];
    float m = fmaxf(l0, fmaxf(l1, l2));
    float e0 = expf(l0 - m), e1 = expf(l1 - m), e2 = expf(l2 - m);
    float inv = 1.f / (e0 + e1 + e2);
    wts[(b0 + tid) * 4 + 0] = e0 * inv;
    wts[(b0 + tid) * 4 + 1] = e1 * inv;
    wts[(b0 + tid) * 4 + 2] = e2 * inv;
  }
  {
    float qpv[3][4];
#pragma unroll
    for (int s = 0; s < 3; ++s)
#pragma unroll
      for (int i = 0; i < 4; ++i) qpv[s][i] = 0.f;
#pragma unroll
    for (int s = 0; s < 3; ++s) {
      const float4* a4 = (const float4*)(attn_w) + ((size_t)s * 256 + e) * 64;
      for (int r = 0; r < 64; ++r) {
        float4 w = a4[r];
#pragma unroll
        for (int i = 0; i < 4; ++i) {
          float4 x = ((const float4*)qk[i])[r];
          qpv[s][i] += w.x * x.x + w.y * x.y + w.z * x.z + w.w * x.w;
        }
      }
    }
    __syncthreads();
#pragma unroll
    for (int s = 0; s < 3; ++s)
#pragma unroll
      for (int i = 0; i < 4; ++i) qp[s][i][e] = qpv[s][i];
  }
  __syncthreads();
  {
    int r = tid;
    float tacc[3][4];
#pragma unroll
    for (int s = 0; s < 3; ++s)
#pragma unroll
      for (int i = 0; i < 4; ++i) tacc[s][i] = 0.f;
    for (int e4 = 0; e4 < 64; ++e4) {
      float4 qv[3][4];
#pragma unroll
      for (int s = 0; s < 3; ++s)
#pragma unroll
        for (int i = 0; i < 4; ++i)
          qv[s][i] = ((const float4*)qp[s][i])[e4];
#pragma unroll
      for (int j = 0; j < 4; ++j) {
        float w = rel_w[(size_t)(e4 * 4 + j) * 256 + r];
#pragma unroll
        for (int s = 0; s < 3; ++s)
#pragma unroll
          for (int i = 0; i < 4; ++i) {
            float q = (j == 0) ? qv[s][i].x : (j == 1) ? qv[s][i].y
                      : (j == 2) ? qv[s][i].z : qv[s][i].w;
            tacc[s][i] = fmaf(q, w, tacc[s][i]);
          }
      }
    }
#pragma unroll
    for (int s = 0; s < 3; ++s)
#pragma unroll
      for (int i = 0; i < 4; ++i)
        t_ws[((size_t)s * B_ + b0 + i) * 256 + r] = tacc[s][i];
  }
}

// ------------- K1: single-pass fused msgs-GEMM + PNA stats + attention -------
// 1024 threads (16 waves), block = one b. Full 208x256 bf16 tile in LDS.
// This round: MFMA-based logit dots (replaces 234 shfl/thread), burst staging
// (MLP=13), vectorized nmeta [NR][12] broadcast reads (364 -> 104 ds-ops/thr).
__global__ __launch_bounds__(1024, 4) void k1_main(
    const float* __restrict__ nb_rel, const float* __restrict__ delta_t,
    const unsigned char* __restrict__ hm_raw, const float* __restrict__ e_emb,
    const float* __restrict__ p_lt1, const float* __restrict__ p_lt2,
    const float* __restrict__ p_sh, const float* __restrict__ p_lgm,
    const unsigned short* __restrict__ rw_bf, const float* __restrict__ t_ws,
    unsigned short* __restrict__ feats) {
  __shared__ __align__(16) struct {
    unsigned int a[NR_ * 132];   // bf16 tile, row stride 264 bf16 (256 data + 8 pad)
    float c[3][NR_];             // unmasked per-scale decay*window weights
    float p[3][NR_];             // logits -> exp scratch
    float nmeta[NR_ * 12];       // stride 12 f32 (48B, 16B-aligned, 2-way banks):
                                 // [0..2]=mf*c, [3]=off(0|1e4), [4..6]=q, [7]=mf
  } sm;
  int b = blockIdx.x;
  int tid = threadIdx.x;
  int lane = tid & 63, wave = tid >> 6;
  int row16 = lane & 15, quad = lane >> 4;

  // ---- mask dtype detection: probe first 1024 bytes ----
  int hasNZoff = 0, hasFP = 0;
  {
    unsigned char cc = hm_raw[tid];
    if ((tid & 3) != 0 && cc != 0) {
      hasNZoff = 1;
      if (cc == 0x3Fu || cc == 0x80u) hasFP = 1;
    }
  }
  int cntNZ = __syncthreads_count(hasNZoff);
  int cntFP = __syncthreads_count(hasFP);
  int mmode = (cntNZ == 0) ? 0 : (cntFP > 0 ? 2 : 1);  // 0=int32 1=bool 2=f32

  float tau1 = __expf(p_lt1[0]);
  float tau2 = __expf(p_lt2[0]) + tau1;
  float sharp = fminf(fmaxf(p_sh[0], 0.1f), 5.0f);
  float gamma = __expf(p_lgm[0]);

  bool mk = false;
  if (tid < NR_) {
    float mf = 0.f, c0 = 0.f, c1 = 0.f, c2 = 0.f;
    if (tid < N_) {
      size_t mi = (size_t)b * N_ + tid;
      if (mmode == 0)      mk = ((const int*)hm_raw)[mi] != 0;
      else if (mmode == 1) mk = hm_raw[mi] != 0;
      else                 mk = ((const float*)hm_raw)[mi] != 0.f;
      float dt = delta_t[mi];
      mf = mk ? 1.f : 0.f;
      float decay = __expf(-gamma * fmaxf(dt, 0.f));
      float wf = 1.f / (1.f + __expf(sharp * (dt - tau1)));
      float wc = 1.f / (1.f + __expf(-sharp * (dt - tau2)));
      float wm = fmaxf(1.f - wf - wc, 0.f);
      c0 = decay * wf; c1 = decay * wm; c2 = decay * wc;
    }
    sm.c[0][tid] = c0; sm.c[1][tid] = c1; sm.c[2][tid] = c2;
    f32x4 w0, w1;
    w0[0] = mf * c0; w0[1] = mf * c1; w0[2] = mf * c2; w0[3] = mk ? 0.f : 1e4f;
    w1[0] = 0.f; w1[1] = 0.f; w1[2] = 0.f; w1[3] = mf;
    *(f32x4*)&sm.nmeta[tid * 12]     = w0;
    *(f32x4*)&sm.nmeta[tid * 12 + 4] = w1;
  }
  int cnt = __syncthreads_count(mk ? 1 : 0);
  float nvf = fmaxf((float)cnt, 1.f);
  bool allinv = (cnt == 0);

  // ---- burst staging: issue all 13 loads (MLP=13), then pack to LDS ----
  {
    const float* src = nb_rel + (size_t)b * N_ * 256;
    float4 xs[NT_];
#pragma unroll
    for (int i = 0; i < NT_; ++i) {
      int n = i * 16 + wave;
      int gn = (n < N_) ? n : (N_ - 1);
      xs[i] = *(const float4*)(src + (size_t)gn * 256 + lane * 4);
    }
#pragma unroll
    for (int i = 0; i < NT_; ++i) {
      uint2 pk;
      pk.x = (unsigned int)f2bf(xs[i].x) | ((unsigned int)f2bf(xs[i].y) << 16);
      pk.y = (unsigned int)f2bf(xs[i].z) | ((unsigned int)f2bf(xs[i].w) << 16);
      *(uint2*)&sm.a[(i * 16 + wave) * 132 + lane * 2] = pk;
    }
  }
  __syncthreads();

  // ---- logit dots via MFMA: wave nt computes araw for its 16 rows, 3 scales.
  // B = t (3 cols, padded to 16 with zeros), same fragment layout as rw_bf.
  if (wave < NT_) {
    bf16x8 tfrag[8];
    const float* tp = t_ws + ((size_t)row16 * B_ + b) * 256;  // OOB ptr for row16>=3, never loaded
#pragma unroll
    for (int ks = 0; ks < 8; ++ks) {
      bf16x8 tv = {0, 0, 0, 0, 0, 0, 0, 0};
      if (row16 < 3) {
        const float* q = tp + ks * 32 + quad * 8;
#pragma unroll
        for (int j = 0; j < 8; ++j) tv[j] = (short)f2bf(q[j]);
      }
      tfrag[ks] = tv;
    }
    f32x4 acc;
#pragma unroll
    for (int cc = 0; cc < 4; ++cc) acc[cc] = 0.f;
#pragma unroll
    for (int ks = 0; ks < 8; ++ks) {
      bf16x8 af = *(const bf16x8*)&sm.a[(wave * 16 + row16) * 132 + ks * 16 + quad * 4];
      acc = __builtin_amdgcn_mfma_f32_16x16x32_bf16(af, tfrag[ks], acc, 0, 0, 0);
    }
    if (row16 < 3) {
#pragma unroll
      for (int rg = 0; rg < 4; ++rg) {
        int n = wave * 16 + quad * 4 + rg;      // C layout: col=lane&15, row=quad*4+rg
        float cw = sm.c[row16][n];
        float mf = sm.nmeta[n * 12 + 7];
        float l = cw * acc[rg] * 0.0625f;
        l = (mf > 0.5f) ? l : -1e4f;            // invalid & padded rows underflow in exp
        if (allinv) l = (n < N_) ? 0.f : -1e4f;
        sm.p[row16][n] = l;
      }
    }
  } else if (wave == NT_) {
    // e_emb tail copy overlapped with the dot phase
    for (int i = lane; i < 256; i += 64) {
      unsigned short v = f2bf(e_emb[(size_t)b * 256 + i]);
      feats[((size_t)0 * B_ + b) * K6_ + 1280 + i] = v;
      feats[((size_t)1 * B_ + b) * K6_ + 1280 + i] = v;
      feats[((size_t)2 * B_ + b) * K6_ + 1280 + i] = v;
    }
  }

  // B-fragment preload (wave owns 16 e-cols) — in flight across the softmax phase
  bf16x8 bfr[8];
  {
    int e = wave * 16 + row16;
#pragma unroll
    for (int ks = 0; ks < 8; ++ks)
      bfr[ks] = *(const bf16x8*)(rw_bf + (size_t)e * 256 + ks * 32 + quad * 8);
  }
  __syncthreads();

  // ---- softmax (waves 0-2): max -> exp(store back) -> normalize into q ----
  if (wave < 3) {
    int s = wave;
    float m = -1e30f;
    for (int n = lane; n < NR_; n += 64) m = fmaxf(m, sm.p[s][n]);
#pragma unroll
    for (int o = 32; o >= 1; o >>= 1) m = fmaxf(m, __shfl_xor(m, o, 64));
    float ssum = 0.f;
    for (int n = lane; n < NR_; n += 64) {
      float ev = __expf(sm.p[s][n] - m);
      sm.p[s][n] = ev;
      ssum += ev;
    }
#pragma unroll
    for (int o = 32; o >= 1; o >>= 1) ssum += __shfl_xor(ssum, o, 64);
    float inv = 1.f / ssum;
    for (int n = lane; n < NR_; n += 64)
      sm.nmeta[n * 12 + 4 + s] = sm.p[s][n] * inv * sm.c[s][n];
  }
  __syncthreads();

  // ---- MFMA GEMM over 13 n-tiles + register stats (wave owns 16 e-cols) ----
  float s_mean[3], s_mx[3], s_mn[3], s_sq[3], s_av[3];
#pragma unroll
  for (int s = 0; s < 3; ++s) {
    s_mean[s] = 0.f; s_mx[s] = -1e30f; s_mn[s] = 1e30f;
    s_sq[s] = 0.f; s_av[s] = 0.f;
  }

  for (int nt = 0; nt < NT_; ++nt) {
    f32x4 acc;
#pragma unroll
    for (int cc = 0; cc < 4; ++cc) acc[cc] = 0.f;
#pragma unroll
    for (int ks = 0; ks < 8; ++ks) {
      bf16x8 af = *(const bf16x8*)&sm.a[(nt * 16 + row16) * 132 + ks * 16 + quad * 4];
      acc = __builtin_amdgcn_mfma_f32_16x16x32_bf16(af, bfr[ks], acc, 0, 0, 0);
    }
    int nb = nt * 16 + quad * 4;
#pragma unroll
    for (int rg = 0; rg < 4; ++rg) {
      const float* nm = &sm.nmeta[(size_t)(nb + rg) * 12];
      f32x4 w0 = *(const f32x4*)nm;        // cm0 cm1 cm2 off   (broadcast b128)
      f32x4 w1 = *(const f32x4*)(nm + 4);  // q0  q1  q2  mf    (broadcast b128)
      float m = acc[rg];
#pragma unroll
      for (int s = 0; s < 3; ++s) {
        float vm = w0[s] * m;
        s_mean[s] += vm;
        s_mx[s] = fmaxf(s_mx[s], vm);
        s_mn[s] = fminf(s_mn[s], fmaf(w0[s], m, w0[3]));
        float cv = fminf(fmaxf(vm, -10.f), 10.f);
        s_sq[s] = fmaf(cv, cv, s_sq[s]);
        s_av[s] = fmaf(w1[s], m, s_av[s]);
      }
    }
  }

  // ---- reduce across quads, write feats (bf16) ----
#pragma unroll
  for (int s = 0; s < 3; ++s) {
    float vmean = s_mean[s];
    vmean += __shfl_xor(vmean, 16, 64); vmean += __shfl_xor(vmean, 32, 64);
    float vmx = s_mx[s];
    vmx = fmaxf(vmx, __shfl_xor(vmx, 16, 64)); vmx = fmaxf(vmx, __shfl_xor(vmx, 32, 64));
    float vmn = s_mn[s];
    vmn = fminf(vmn, __shfl_xor(vmn, 16, 64)); vmn = fminf(vmn, __shfl_xor(vmn, 32, 64));
    float vsq = s_sq[s];
    vsq += __shfl_xor(vsq, 16, 64); vsq += __shfl_xor(vsq, 32, 64);
    float vav = s_av[s];
    vav += __shfl_xor(vav, 16, 64); vav += __shfl_xor(vav, 32, 64);
    if (lane < 16) {
      int e = wave * 16 + lane;
      size_t base = ((size_t)s * B_ + b) * K6_;
      float meanv = vmean / nvf;
      float stdv = sqrtf(fmaxf(vsq / nvf - meanv * meanv, 1e-6f));
      float mnv = fminf(fmaxf(vmn, -1e4f), 1e4f);
      feats[base + e] = f2bf(meanv);
      feats[base + 256 + e] = f2bf(vmx);
      feats[base + 512 + e] = f2bf(mnv);
      feats[base + 768 + e] = f2bf(stdv);
      feats[base + 1024 + e] = f2bf(vav);
    }
  }
}

// ------- K2: h = feats(bf16) @ sp_w^T + bias -> hbuf (pre-LN, fp32) -------
__global__ __launch_bounds__(256) void k2_kernel(
    const unsigned short* __restrict__ feats, const unsigned short* __restrict__ spw_bf,
    const float* __restrict__ sp_b, float* __restrict__ hbuf) {
  __shared__ __align__(16) unsigned int a[16 * 132];
  int id = blockIdx.x;
  int s = id >> 7;
  int rem = id & 127;
  int b0 = (rem >> 1) * 16;
  int e0 = (rem & 1) * 128;
  int tid = threadIdx.x, lane = tid & 63, wave = tid >> 6;
  int row16 = lane & 15, quad = lane >> 4;
  f32x4 acc[2];
#pragma unroll
  for (int t = 0; t < 2; ++t)
#pragma unroll
    for (int cc = 0; cc < 4; ++cc) acc[t][cc] = 0.f;

  for (int kc = 0; kc < 6; ++kc) {
    __syncthreads();
    for (int j = tid; j < 512; j += 256) {
      int rw = j >> 5, ck = j & 31;
      bf16x8 v = *(const bf16x8*)(feats + ((size_t)s * B_ + b0 + rw) * K6_ + kc * 256 + ck * 8);
      *(bf16x8*)((unsigned short*)&a[rw * 132] + ck * 8) = v;
    }
    __syncthreads();
#pragma unroll
    for (int ks = 0; ks < 8; ++ks) {
      bf16x8 af = *(const bf16x8*)&a[row16 * 132 + ks * 16 + quad * 4];
#pragma unroll
      for (int t = 0; t < 2; ++t) {
        int e = e0 + wave * 32 + t * 16 + row16;
        bf16x8 bfr = *(const bf16x8*)(spw_bf + ((size_t)s * E_ + e) * K6_ + kc * 256 + ks * 32 + quad * 8);
        acc[t] = __builtin_amdgcn_mfma_f32_16x16x32_bf16(af, bfr, acc[t], 0, 0, 0);
      }
    }
  }
#pragma unroll
  for (int t = 0; t < 2; ++t) {
    int e = e0 + wave * 32 + t * 16 + row16;
    float bias = sp_b[s * 256 + e];
#pragma unroll
    for (int rg = 0; rg < 4; ++rg) {
      int rw = quad * 4 + rg;
      hbuf[((size_t)s * B_ + b0 + rw) * 256 + e] = acc[t][rg] + bias;
    }
  }
}

// ------- K3: per b: for each s LN+gelu, weighted sum, final LN -> out -------
__global__ __launch_bounds__(256) void k3_kernel(
    const float* __restrict__ hbuf, const float* __restrict__ wts,
    const float* __restrict__ ln_g, const float* __restrict__ ln_b,
    const float* __restrict__ on_g, const float* __restrict__ on_b,
    float* __restrict__ out) {
  __shared__ float rs[4], rq[4];
  int b = blockIdx.x, tid = threadIdx.x, lane = tid & 63, wave = tid >> 6;
  float o = 0.f;
#pragma unroll
  for (int s = 0; s < 3; ++s) {
    float h = hbuf[((size_t)s * B_ + b) * 256 + tid];
    float sum = h, sq = h * h;
#pragma unroll
    for (int off = 32; off >= 1; off >>= 1) {
      sum += __shfl_xor(sum, off, 64);
      sq += __shfl_xor(sq, off, 64);
    }
    if (lane == 0) { rs[wave] = sum; rq[wave] = sq; }
    __syncthreads();
    float ts = rs[0] + rs[1] + rs[2] + rs[3];
    float tq = rq[0] + rq[1] + rq[2] + rq[3];
    __syncthreads();
    float mu = ts * (1.f / 256.f);
    float var = tq * (1.f / 256.f) - mu * mu;
    float rstd = rsqrtf(var + 1e-5f);
    float v = (h - mu) * rstd * ln_g[s * 256 + tid] + ln_b[s * 256 + tid];
    o += wts[b * 4 + s] * gelu_exact(v);
  }
  float sum = o, sq = o * o;
#pragma unroll
  for (int off = 32; off >= 1; off >>= 1) {
    sum += __shfl_xor(sum, off, 64);
    sq += __shfl_xor(sq, off, 64);
  }
  if (lane == 0) { rs[wave] = sum; rq[wave] = sq; }
  __syncthreads();
  float ts = rs[0] + rs[1] + rs[2] + rs[3];
  float tq = rq[0] + rq[1] + rq[2] + rq[3];
  float mu = ts * (1.f / 256.f);
  float var = tq * (1.f / 256.f) - mu * mu;
  float rstd = rsqrtf(var + 1e-5f);
  out[(size_t)b * 256 + tid] = (o - mu) * rstd * on_g[tid] + on_b[tid];
}

extern "C" void kernel_launch(void* const* d_in, const int* in_sizes, int n_in,
                              void* d_out, int out_size, void* d_ws, size_t ws_size,
                              hipStream_t stream) {
  const float* e_emb   = (const float*)d_in[0];
  const float* nb_rel  = (const float*)d_in[1];
  const float* delta_t = (const float*)d_in[2];
  const float* r_emb   = (const float*)d_in[3];
  const unsigned char* hist_mask = (const unsigned char*)d_in[4]; // dtype auto-detected
  const float* rel_w   = (const float*)d_in[5];
  const float* lt1     = (const float*)d_in[6];
  const float* lt2     = (const float*)d_in[7];
  const float* shp     = (const float*)d_in[8];
  const float* lgm     = (const float*)d_in[9];
  const float* attn_w  = (const float*)d_in[10];
  const float* sp_w    = (const float*)d_in[11];
  const float* sp_b    = (const float*)d_in[12];
  const float* ln_g    = (const float*)d_in[13];
  const float* ln_b    = (const float*)d_in[14];
  const float* csq_w   = (const float*)d_in[15];
  const float* csq_b   = (const float*)d_in[16];
  const float* csl_w   = (const float*)d_in[17];
  const float* csl_b   = (const float*)d_in[18];
  const float* on_g    = (const float*)d_in[19];
  const float* on_b    = (const float*)d_in[20];
  float* out = (float*)d_out;

  char* ws = (char*)d_ws;
  unsigned short* rw_bf  = (unsigned short*)(ws + 0);         // 131072 B
  unsigned short* spw_bf = (unsigned short*)(ws + 131072);    // 2359296 B
  float* t_ws   = (float*)(ws + 2490368);                     // 3 MB
  float* wts    = (float*)(ws + 5636096);                     // 16 KB
  unsigned short* feats = (unsigned short*)(ws + 5652480);    // 9.44 MB (bf16)
  float* hbuf   = (float*)(ws + 15089664);                    // 3 MB (total ~18.2 MB)

  hipLaunchKernelGGL(k_cast, dim3(4864), dim3(256), 0, stream, rel_w, sp_w, rw_bf, spw_bf);
  hipLaunchKernelGGL(k_prep, dim3(256), dim3(256), 0, stream, r_emb, rel_w, csq_w, csq_b,
                     csl_w, csl_b, attn_w, t_ws, wts);
  hipLaunchKernelGGL(k1_main, dim3(1024), dim3(1024), 0, stream, nb_rel, delta_t, hist_mask,
                     e_emb, lt1, lt2, shp, lgm, rw_bf, t_ws, feats);
  hipLaunchKernelGGL(k2_kernel, dim3(384), dim3(256), 0, stream, feats, spw_bf, sp_b, hbuf);
  hipLaunchKernelGGL(k3_kernel, dim3(1024), dim3(256), 0, stream, hbuf, wts, ln_g, ln_b,
                     on_g, on_b, out);
}